// Round 2
// baseline (185.433 us; speedup 1.0000x reference)
//
#include <hip/hip_runtime.h>
#include <hip/hip_bf16.h>
#include <stdint.h>

#define NQ 8192
#define NT 8192
#define DIM 512
#define GAMMA 1.0f

typedef __hip_bfloat16 bf16;
using bf16x8 = __attribute__((ext_vector_type(8))) short;
using f32x4  = __attribute__((ext_vector_type(4))) float;

typedef __attribute__((address_space(1))) void* gas1_t;
typedef __attribute__((address_space(3))) void* las3_t;

// ---------------- zero the output (harness poisons it with 0xAA) ------------
__global__ void zero_out_k(float* __restrict__ out) {
    out[blockIdx.x * 256 + threadIdx.x] = 0.0f;
}

// ---------------- prepass: fp32 -> bf16 + row norms -------------------------
// one block per row (16384 blocks); 256 threads, 2 elems/thread
__global__ void prep_k(const float* __restrict__ X, const float* __restrict__ T,
                       bf16* __restrict__ Xb, bf16* __restrict__ Tb,
                       float* __restrict__ x2, float* __restrict__ y2) {
    int row = blockIdx.x;
    const float* src;
    bf16* dst;
    float* nrm;
    int r;
    if (row < NQ) { r = row;      src = X + (size_t)r * DIM; dst = Xb + (size_t)r * DIM; nrm = x2; }
    else          { r = row - NQ; src = T + (size_t)r * DIM; dst = Tb + (size_t)r * DIM; nrm = y2; }
    int t = threadIdx.x;
    float2 v = reinterpret_cast<const float2*>(src)[t];
    float s = v.x * v.x + v.y * v.y;
    __hip_bfloat162 b;
    b.x = __float2bfloat16(v.x);
    b.y = __float2bfloat16(v.y);
    reinterpret_cast<__hip_bfloat162*>(dst)[t] = b;
#pragma unroll
    for (int off = 32; off > 0; off >>= 1) s += __shfl_down(s, off, 64);
    __shared__ float red[4];
    if ((t & 63) == 0) red[t >> 6] = s;
    __syncthreads();
    if (t == 0) nrm[r] = red[0] + red[1] + red[2] + red[3];
}

// ---------------- main: bf16 MFMA GEMM + fused RBF epilogue -----------------
// grid.x = q-blocks (64), grid.y = t-blocks (64); 256 threads = 4 waves (2x2)
// Tile 128x128, BK=32. A = train rows (M = t), B = X rows (N = q), both [row][k].
// D fragment: col = lane&15 (q), row = (lane>>4)*4 + reg (t)  -> t-reduction is
// 4 regs + shfl_xor(16,32); one atomicAdd per (q, block-t).
__global__ __launch_bounds__(256) void krr_mfma_k(
    const bf16* __restrict__ Tb, const bf16* __restrict__ Xb,
    const float* __restrict__ x2, const float* __restrict__ y2,
    const float* __restrict__ coef, float* __restrict__ out) {

    __shared__ bf16 sA[128 * 32];   // t-tile  [128][32]
    __shared__ bf16 sB[128 * 32];   // q-tile  [128][32]

    const int tid  = threadIdx.x;
    const int w    = tid >> 6;
    const int lane = tid & 63;
    const int wr   = w >> 1;        // t quadrant (0/1)
    const int wc   = w & 1;         // q quadrant (0/1)

    const int qBlk = blockIdx.x * 128;
    const int tBlk = blockIdx.y * 128;

    const int ldr = lane >> 2;        // row within a 16-row staging group
    const int ldc = (lane & 3) * 8;   // k-element offset (8 bf16 = 16 B)

    f32x4 acc[4][4];
    const f32x4 zero4 = {0.f, 0.f, 0.f, 0.f};
#pragma unroll
    for (int m = 0; m < 4; ++m)
#pragma unroll
        for (int n = 0; n < 4; ++n) acc[m][n] = zero4;

    for (int k0 = 0; k0 < DIM; k0 += 32) {
        // ---- stage: each wave fills 2x16 rows of each tile via global_load_lds
#pragma unroll
        for (int j = 0; j < 2; ++j) {
            const int rows = w * 32 + j * 16;
            const bf16* ga = Tb + (size_t)(tBlk + rows + ldr) * DIM + k0 + ldc;
            __builtin_amdgcn_global_load_lds((gas1_t)ga, (las3_t)(&sA[rows * 32]), 16, 0, 0);
            const bf16* gb = Xb + (size_t)(qBlk + rows + ldr) * DIM + k0 + ldc;
            __builtin_amdgcn_global_load_lds((gas1_t)gb, (las3_t)(&sB[rows * 32]), 16, 0, 0);
        }
        __syncthreads();

        bf16x8 af[4], bfr[4];
#pragma unroll
        for (int m = 0; m < 4; ++m)
            af[m] = *reinterpret_cast<const bf16x8*>(
                &sA[(wr * 64 + m * 16 + (lane & 15)) * 32 + (lane >> 4) * 8]);
#pragma unroll
        for (int n = 0; n < 4; ++n)
            bfr[n] = *reinterpret_cast<const bf16x8*>(
                &sB[(wc * 64 + n * 16 + (lane & 15)) * 32 + (lane >> 4) * 8]);

#pragma unroll
        for (int m = 0; m < 4; ++m)
#pragma unroll
            for (int n = 0; n < 4; ++n)
                acc[m][n] = __builtin_amdgcn_mfma_f32_16x16x32_bf16(af[m], bfr[n], acc[m][n], 0, 0, 0);

        __syncthreads();
    }

    // ---- epilogue: w = exp(-gamma*max(x2+y2-2*dot,0))*coef, reduce over t ----
    float y2v[16], cfv[16];
#pragma unroll
    for (int m = 0; m < 4; ++m) {
        const int tb = tBlk + wr * 64 + m * 16 + ((lane >> 4) << 2);
#pragma unroll
        for (int r = 0; r < 4; ++r) {
            y2v[m * 4 + r] = y2[tb + r];
            cfv[m * 4 + r] = coef[tb + r];
        }
    }
#pragma unroll
    for (int n = 0; n < 4; ++n) {
        const int q = qBlk + wc * 64 + n * 16 + (lane & 15);
        const float xq = x2[q];
        float s = 0.f;
#pragma unroll
        for (int m = 0; m < 4; ++m) {
#pragma unroll
            for (int r = 0; r < 4; ++r) {
                const float d  = acc[m][n][r];
                const float sq = fmaxf(xq + y2v[m * 4 + r] - 2.0f * d, 0.f);
                s += __expf(-GAMMA * sq) * cfv[m * 4 + r];
            }
        }
        s += __shfl_xor(s, 16, 64);
        s += __shfl_xor(s, 32, 64);
        if (lane < 16) atomicAdd(&out[q], s);
    }
}

// ---------------- fallback: plain fp32, no workspace ------------------------
__global__ void krr_naive_k(const float* __restrict__ X, const float* __restrict__ T,
                            const float* __restrict__ coef, float* __restrict__ out) {
    __shared__ float xq[DIM];
    const int q = blockIdx.x;
    for (int i = threadIdx.x; i < DIM; i += 256) xq[i] = X[(size_t)q * DIM + i];
    __syncthreads();
    float s2 = 0.f;
    for (int i = 0; i < DIM; ++i) s2 += xq[i] * xq[i];
    float acc = 0.f;
    for (int t = threadIdx.x; t < NT; t += 256) {
        const float* ty = T + (size_t)t * DIM;
        float dot = 0.f, yy = 0.f;
        for (int i = 0; i < DIM; ++i) { float yv = ty[i]; dot += xq[i] * yv; yy += yv * yv; }
        float sq = fmaxf(s2 + yy - 2.0f * dot, 0.f);
        acc += __expf(-GAMMA * sq) * coef[t];
    }
#pragma unroll
    for (int off = 32; off > 0; off >>= 1) acc += __shfl_down(acc, off, 64);
    __shared__ float red[4];
    if ((threadIdx.x & 63) == 0) red[threadIdx.x >> 6] = acc;
    __syncthreads();
    if (threadIdx.x == 0) out[q] = red[0] + red[1] + red[2] + red[3];
}

extern "C" void kernel_launch(void* const* d_in, const int* in_sizes, int n_in,
                              void* d_out, int out_size, void* d_ws, size_t ws_size,
                              hipStream_t stream) {
    const float* X    = (const float*)d_in[0];
    const float* T    = (const float*)d_in[1];
    const float* coef = (const float*)d_in[2];
    float* out = (float*)d_out;

    zero_out_k<<<NQ / 256, 256, 0, stream>>>(out);

    const size_t need = (size_t)(NQ + NT) * DIM * sizeof(bf16) + (size_t)(NQ + NT) * sizeof(float);
    if (ws_size >= need) {
        bf16* Xb  = (bf16*)d_ws;
        bf16* Tb  = Xb + (size_t)NQ * DIM;
        float* x2 = (float*)(Tb + (size_t)NT * DIM);
        float* y2 = x2 + NQ;
        prep_k<<<NQ + NT, 256, 0, stream>>>(X, T, Xb, Tb, x2, y2);
        dim3 grid(NQ / 128, NT / 128);
        krr_mfma_k<<<grid, 256, 0, stream>>>(Tb, Xb, x2, y2, coef, out);
    } else {
        krr_naive_k<<<NQ, 256, 0, stream>>>(X, T, coef, out);
    }
}

// Round 3
// 149.860 us; speedup vs baseline: 1.2374x; 1.2374x over previous
//
#include <hip/hip_runtime.h>
#include <hip/hip_bf16.h>
#include <stdint.h>

#define NQ 8192
#define NT 8192
#define DIM 512
#define BK 32
#define NKT (DIM / BK)      // 16 K-tiles
#define BM 256              // t rows per block
#define BN 256              // q rows per block
#define BUF_ELEMS ((BM + BN) * BK)   // 16384 bf16 = 32 KB per buffer

typedef __hip_bfloat16 bf16;
using bf16x8  = __attribute__((ext_vector_type(8))) short;
using f32x4   = __attribute__((ext_vector_type(4))) float;
using short8v = __attribute__((ext_vector_type(8))) short;

typedef __attribute__((address_space(1))) void* gas1_t;
typedef __attribute__((address_space(3))) void* las3_t;

// ---------------- zero the output (harness poisons with 0xAA) ---------------
__global__ void zero_out_k(float* __restrict__ out) {
    out[blockIdx.x * 256 + threadIdx.x] = 0.0f;
}

// ---------------- prepass: fp32 -> bf16 + row norms -------------------------
// 2048 blocks x 256 thr (4 waves); each wave handles 2 rows, float4 loads.
__global__ void prep_k(const float* __restrict__ X, const float* __restrict__ T,
                       bf16* __restrict__ Xb, bf16* __restrict__ Tb,
                       float* __restrict__ x2, float* __restrict__ y2) {
    const int w    = threadIdx.x >> 6;
    const int lane = threadIdx.x & 63;
    const int wid  = blockIdx.x * 4 + w;          // 0..8191
#pragma unroll
    for (int rr = 0; rr < 2; ++rr) {
        const int row = wid * 2 + rr;             // 0..16383
        const float* src; bf16* dst; float* nrm; int r;
        if (row < NQ) { r = row;      src = X + (size_t)r * DIM; dst = Xb + (size_t)r * DIM; nrm = x2; }
        else          { r = row - NQ; src = T + (size_t)r * DIM; dst = Tb + (size_t)r * DIM; nrm = y2; }
        const float4 v0 = reinterpret_cast<const float4*>(src)[lane * 2];
        const float4 v1 = reinterpret_cast<const float4*>(src)[lane * 2 + 1];
        float s = v0.x*v0.x + v0.y*v0.y + v0.z*v0.z + v0.w*v0.w
                + v1.x*v1.x + v1.y*v1.y + v1.z*v1.z + v1.w*v1.w;
        short8v pk;
        pk[0] = (short)__bfloat16_as_ushort(__float2bfloat16(v0.x));
        pk[1] = (short)__bfloat16_as_ushort(__float2bfloat16(v0.y));
        pk[2] = (short)__bfloat16_as_ushort(__float2bfloat16(v0.z));
        pk[3] = (short)__bfloat16_as_ushort(__float2bfloat16(v0.w));
        pk[4] = (short)__bfloat16_as_ushort(__float2bfloat16(v1.x));
        pk[5] = (short)__bfloat16_as_ushort(__float2bfloat16(v1.y));
        pk[6] = (short)__bfloat16_as_ushort(__float2bfloat16(v1.z));
        pk[7] = (short)__bfloat16_as_ushort(__float2bfloat16(v1.w));
        reinterpret_cast<short8v*>(dst)[lane] = pk;
#pragma unroll
        for (int off = 32; off; off >>= 1) s += __shfl_xor(s, off, 64);
        if (lane == 0) nrm[r] = s;
    }
}

// ---------------- staging: one K-tile (A: 256 t-rows, B: 256 q-rows) --------
// LDS image is XOR-swizzled: logical (row R, 16B-chunk C) lives at physical
// chunk C ^ ((R>>1)&3).  global_load_lds writes linearly (base + 16*lane), so
// we pre-swizzle the per-lane GLOBAL source (rule 21: both-sides-or-neither).
__device__ __forceinline__ void stage_tile(
    const bf16* __restrict__ Tb, const bf16* __restrict__ Xb,
    int tBlk, int qBlk, int kt, bf16* sA, bf16* sB, int w, int lane) {
    const int k0 = kt * BK;
    const int rl = lane >> 2;                 // row within 16-row group
    const int sw = (rl >> 1) & 3;             // swizzle key (base rows are %16==0)
    const int c  = (lane & 3) ^ sw;           // global chunk this lane fetches
#pragma unroll
    for (int j = 0; j < 2; ++j) {
        const int R0 = j * 128 + w * 16;      // wave-uniform
        const int R  = R0 + rl;
        const bf16* ga = Tb + (size_t)(tBlk + R) * DIM + k0 + c * 8;
        __builtin_amdgcn_global_load_lds((gas1_t)ga, (las3_t)(sA + R0 * BK), 16, 0, 0);
        const bf16* gb = Xb + (size_t)(qBlk + R) * DIM + k0 + c * 8;
        __builtin_amdgcn_global_load_lds((gas1_t)gb, (las3_t)(sB + R0 * BK), 16, 0, 0);
    }
}

// ---------------- compute: one K-tile, per-wave 128x64 (8x4 frags) ----------
__device__ __forceinline__ void compute_tile(
    const bf16* sA, const bf16* sB, int wm, int wn, int lane, f32x4 (&acc)[8][4]) {
    const int fr = lane & 15;
    const int fc = lane >> 4;
    const int swz = (fc ^ ((fr >> 1) & 3)) * 8;   // physical chunk offset (elems)
    bf16x8 a[8], b[4];
#pragma unroll
    for (int m = 0; m < 8; ++m) {
        const int R = wm * 128 + m * 16 + fr;
        a[m] = *reinterpret_cast<const bf16x8*>(sA + R * BK + swz);
    }
#pragma unroll
    for (int n = 0; n < 4; ++n) {
        const int R = wn * 64 + n * 16 + fr;
        b[n] = *reinterpret_cast<const bf16x8*>(sB + R * BK + swz);
    }
    __builtin_amdgcn_s_setprio(1);
#pragma unroll
    for (int m = 0; m < 8; ++m)
#pragma unroll
        for (int n = 0; n < 4; ++n)
            acc[m][n] = __builtin_amdgcn_mfma_f32_16x16x32_bf16(a[m], b[n], acc[m][n], 0, 0, 0);
    __builtin_amdgcn_s_setprio(0);
}

#define WAIT_BAR(N)                                              \
    asm volatile("s_waitcnt vmcnt(" #N ")" ::: "memory");        \
    __builtin_amdgcn_s_barrier();                                \
    __builtin_amdgcn_sched_barrier(0);

// ---------------- main: 256x256 tile, 8 waves, depth-2 counted-vmcnt --------
__global__ __launch_bounds__(512, 2) void krr_mfma_k(
    const bf16* __restrict__ Tb, const bf16* __restrict__ Xb,
    const float* __restrict__ x2, const float* __restrict__ y2,
    const float* __restrict__ coef, float* __restrict__ out) {

    __shared__ bf16 lds[3 * BUF_ELEMS];       // 96 KB: 3 x (A 16KB + B 16KB)

    const int tid  = threadIdx.x;
    const int w    = tid >> 6;
    const int lane = tid & 63;
    const int wm   = w >> 2;                  // t half (0/1): rows wm*128..+127
    const int wn   = w & 3;                   // q quarter:    rows wn*64..+63

    const int qBlk = blockIdx.x * BN;
    const int tBlk = blockIdx.y * BM;

    f32x4 acc[8][4];
    const f32x4 z4 = {0.f, 0.f, 0.f, 0.f};
#pragma unroll
    for (int m = 0; m < 8; ++m)
#pragma unroll
        for (int n = 0; n < 4; ++n) acc[m][n] = z4;

    // prologue: stage tiles 0,1 -> bufs 0,1 (8 loads/wave in flight)
    stage_tile(Tb, Xb, tBlk, qBlk, 0, lds,             lds + BM * BK,             w, lane);
    stage_tile(Tb, Xb, tBlk, qBlk, 1, lds + BUF_ELEMS, lds + BUF_ELEMS + BM * BK, w, lane);

    int bc = 0, bs = 2;                       // compute buf for t; stage buf for t+2
    for (int t = 0; t < NKT - 2; ++t) {       // 14 iters
        WAIT_BAR(4)                           // tile t landed (all waves)
        stage_tile(Tb, Xb, tBlk, qBlk, t + 2,
                   lds + bs * BUF_ELEMS, lds + bs * BUF_ELEMS + BM * BK, w, lane);
        compute_tile(lds + bc * BUF_ELEMS, lds + bc * BUF_ELEMS + BM * BK, wm, wn, lane, acc);
        bc = (bc == 2) ? 0 : bc + 1;
        bs = (bs == 2) ? 0 : bs + 1;
    }
    WAIT_BAR(4)                               // t = 14 (bc = 2)
    compute_tile(lds + bc * BUF_ELEMS, lds + bc * BUF_ELEMS + BM * BK, wm, wn, lane, acc);
    bc = (bc == 2) ? 0 : bc + 1;
    WAIT_BAR(0)                               // t = 15 (bc = 0)
    compute_tile(lds + bc * BUF_ELEMS, lds + bc * BUF_ELEMS + BM * BK, wm, wn, lane, acc);

    // ---- epilogue: s += exp(-(x2+y2-2*dot)) * coef, reduce over t ----------
    float s[4], x2q[4];
#pragma unroll
    for (int n = 0; n < 4; ++n) {
        s[n]   = 0.f;
        x2q[n] = x2[qBlk + wn * 64 + n * 16 + (lane & 15)];
    }
#pragma unroll
    for (int m = 0; m < 8; ++m) {
        const int tb = tBlk + wm * 128 + m * 16 + ((lane >> 4) << 2);
        float y2v[4], cfv[4];
#pragma unroll
        for (int r = 0; r < 4; ++r) { y2v[r] = y2[tb + r]; cfv[r] = coef[tb + r]; }
#pragma unroll
        for (int n = 0; n < 4; ++n)
#pragma unroll
            for (int r = 0; r < 4; ++r) {
                const float d  = acc[m][n][r];
                const float sq = fmaxf(x2q[n] + y2v[r] - 2.0f * d, 0.f);
                s[n] += __expf(-sq) * cfv[r];
            }
    }
#pragma unroll
    for (int n = 0; n < 4; ++n) {
        float v = s[n];
        v += __shfl_xor(v, 16, 64);
        v += __shfl_xor(v, 32, 64);
        if (lane < 16) atomicAdd(&out[qBlk + wn * 64 + n * 16 + lane], v);
    }
}

// ---------------- fallback: plain fp32, no workspace ------------------------
__global__ void krr_naive_k(const float* __restrict__ X, const float* __restrict__ T,
                            const float* __restrict__ coef, float* __restrict__ out) {
    __shared__ float xq[DIM];
    const int q = blockIdx.x;
    for (int i = threadIdx.x; i < DIM; i += 256) xq[i] = X[(size_t)q * DIM + i];
    __syncthreads();
    float s2 = 0.f;
    for (int i = 0; i < DIM; ++i) s2 += xq[i] * xq[i];
    float acc = 0.f;
    for (int t = threadIdx.x; t < NT; t += 256) {
        const float* ty = T + (size_t)t * DIM;
        float dot = 0.f, yy = 0.f;
        for (int i = 0; i < DIM; ++i) { float yv = ty[i]; dot += xq[i] * yv; yy += yv * yv; }
        float sq = fmaxf(s2 + yy - 2.0f * dot, 0.f);
        acc += __expf(-sq) * coef[t];
    }
#pragma unroll
    for (int off = 32; off > 0; off >>= 1) acc += __shfl_down(acc, off, 64);
    __shared__ float red[4];
    if ((threadIdx.x & 63) == 0) red[threadIdx.x >> 6] = acc;
    __syncthreads();
    if (threadIdx.x == 0) out[q] = red[0] + red[1] + red[2] + red[3];
}

extern "C" void kernel_launch(void* const* d_in, const int* in_sizes, int n_in,
                              void* d_out, int out_size, void* d_ws, size_t ws_size,
                              hipStream_t stream) {
    const float* X    = (const float*)d_in[0];
    const float* T    = (const float*)d_in[1];
    const float* coef = (const float*)d_in[2];
    float* out = (float*)d_out;

    zero_out_k<<<NQ / 256, 256, 0, stream>>>(out);

    const size_t need = (size_t)(NQ + NT) * DIM * sizeof(bf16) + (size_t)(NQ + NT) * sizeof(float);
    if (ws_size >= need) {
        bf16* Xb  = (bf16*)d_ws;
        bf16* Tb  = Xb + (size_t)NQ * DIM;
        float* x2 = (float*)(Tb + (size_t)NT * DIM);
        float* y2 = x2 + NQ;
        prep_k<<<2048, 256, 0, stream>>>(X, T, Xb, Tb, x2, y2);
        dim3 grid(NQ / BN, NT / BM);
        krr_mfma_k<<<grid, 512, 0, stream>>>(Tb, Xb, x2, y2, coef, out);
    } else {
        krr_naive_k<<<NQ, 256, 0, stream>>>(X, T, coef, out);
    }
}